// Round 6
// baseline (75.625 us; speedup 1.0000x reference)
//
#include <hip/hip_runtime.h>
#include <hip/hip_bf16.h>
#include <math.h>

typedef float f32x4 __attribute__((ext_vector_type(4)));
typedef float f32x16 __attribute__((ext_vector_type(16)));
typedef __bf16 bf16x8 __attribute__((ext_vector_type(8)));
typedef unsigned short ushort4_t __attribute__((ext_vector_type(4)));
typedef unsigned int u32x4 __attribute__((ext_vector_type(4)));

#define B_ 8
#define S_ 2048
#define D_ 1024
#define H_ 64

static __device__ __forceinline__ unsigned short f2bf(float f) {
    __bf16 h = (__bf16)f;
    return __builtin_bit_cast(unsigned short, h);
}
static __device__ __forceinline__ unsigned int pkbf(float lo, float hi) {
    return ((unsigned int)f2bf(hi) << 16) | (unsigned int)f2bf(lo);
}

static __device__ __forceinline__ void gload16(const void* g, void* l) {
    __builtin_amdgcn_global_load_lds(
        (__attribute__((address_space(1))) void*)(void*)g,
        (__attribute__((address_space(3))) void*)l, 16, 0, 0);
}

// Stage Wt tile: 192 rows x 128B, global row stride 2048B. 1536 chunks, 6 per wave-lane.
static __device__ __forceinline__ void stage_wt(const unsigned short* Wt, int kt, char* dst, int w, int lane) {
#pragma unroll
    for (int i = 0; i < 6; ++i) {
        int ch = w * 384 + i * 64 + lane;
        int p = ch * 16;
        int rr = p >> 7;
        int off = (p ^ ((rr & 7) << 4)) & 127;
        const char* gsrc = (const char*)Wt + (size_t)rr * 2048 + kt * 128 + off;
        gload16(gsrc, dst + (w * 384 + i * 64) * 16);
    }
}

// ---------------- Kernel 0: W [1024][64] f32 -> Wt [3][64][1024] bf16 ----------------
__global__ __launch_bounds__(256) void prep_w_kernel(const float* __restrict__ Wq,
                                                     const float* __restrict__ Wk,
                                                     const float* __restrict__ Wv,
                                                     unsigned short* __restrict__ Wt) {
    __shared__ float tile[64][65];
    int which = blockIdx.y;
    const float* W = (which == 0) ? Wq : ((which == 1) ? Wk : Wv);
    int k0 = blockIdx.x * 64;
    int t = threadIdx.x;
    int r = t >> 2, c0 = (t & 3) * 16;
#pragma unroll
    for (int j = 0; j < 16; ++j) tile[r][c0 + j] = W[(size_t)(k0 + r) * 64 + c0 + j];
    __syncthreads();
    unsigned short* dst = Wt + (size_t)(which * 64 + r) * 1024 + k0 + c0;
#pragma unroll
    for (int j = 0; j < 16; ++j) dst[j] = f2bf(tile[c0 + j][r]);
}

// ---------------- Kernel 1: qkv projection, 32-row M-tiles ----------------
__global__ __launch_bounds__(256) void qkv_kernel(const float* __restrict__ x,
                                                  const unsigned short* __restrict__ Wt,
                                                  unsigned short* __restrict__ qw,
                                                  unsigned short* __restrict__ kw,
                                                  unsigned short* __restrict__ vw) {
    __shared__ __align__(16) char lds[4096 + 2 * 24576];
    char* xs = lds;
    int t = threadIdx.x, lane = t & 63, w = t >> 6, g = lane >> 4, qi = lane & 15;
    int m0 = blockIdx.x * 32;
    int row = t >> 3, seg = t & 7;
    const float* xrow = x + (size_t)(m0 + row) * 1024 + seg * 8;

    f32x4 acc[6];
#pragma unroll
    for (int n = 0; n < 6; ++n) acc[n] = (f32x4){0.f, 0.f, 0.f, 0.f};

    float4 xr0 = *(const float4*)(xrow + 0);
    float4 xr1 = *(const float4*)(xrow + 4);
    stage_wt(Wt, 0, lds + 4096, w, lane);

    int rh = w & 1, ch = w >> 1;
    int cur = 0;
    for (int kt = 0; kt < 16; ++kt) {
        bf16x8 pk;
        pk[0] = (__bf16)xr0.x; pk[1] = (__bf16)xr0.y; pk[2] = (__bf16)xr0.z; pk[3] = (__bf16)xr0.w;
        pk[4] = (__bf16)xr1.x; pk[5] = (__bf16)xr1.y; pk[6] = (__bf16)xr1.z; pk[7] = (__bf16)xr1.w;
        int b0 = row * 128 + seg * 16;
        *(bf16x8*)(xs + (b0 ^ ((row & 7) << 4))) = pk;
        __syncthreads();

        if (kt < 15) {
            const float* nsrc = xrow + (kt + 1) * 64;
            xr0 = *(const float4*)(nsrc + 0);
            xr1 = *(const float4*)(nsrc + 4);
            stage_wt(Wt, kt + 1, lds + 4096 + (cur ^ 1) * 24576, w, lane);
        }
        const char* wsb = lds + 4096 + cur * 24576;

        int arow = rh * 16 + qi;
        int swa = (arow & 7) << 4;
#pragma unroll
        for (int ks = 0; ks < 2; ++ks) {
            bf16x8 a = *(const bf16x8*)(xs + ((arow * 128 + ks * 64 + g * 16) ^ swa));
#pragma unroll
            for (int n = 0; n < 6; ++n) {
                int brow = ch * 96 + n * 16 + qi;
                bf16x8 bb = *(const bf16x8*)(wsb + ((brow * 128 + ks * 64 + g * 16) ^ ((brow & 7) << 4)));
                acc[n] = __builtin_amdgcn_mfma_f32_16x16x32_bf16(a, bb, acc[n], 0, 0, 0);
            }
        }
        __syncthreads();
        cur ^= 1;
    }

    int bq = m0 >> 11;
    int sl = (m0 & 2047) + rh * 16 + g * 4;
    int rowg = m0 + rh * 16 + g * 4;
#pragma unroll
    for (int n = 0; n < 6; ++n) {
        int c = ch * 96 + n * 16;
        int which = c >> 6;
        int col = (c & 63) + qi;
        if (which == 0) {
#pragma unroll
            for (int r = 0; r < 4; ++r)
                qw[(size_t)(rowg + r) * 64 + col] = f2bf(acc[n][r]);
        } else if (which == 1) {
#pragma unroll
            for (int r = 0; r < 4; ++r)
                kw[(size_t)(rowg + r) * 64 + col] = f2bf(acc[n][r]);
        } else {
            ushort4_t pv;
            pv[0] = f2bf(acc[n][0]); pv[1] = f2bf(acc[n][1]);
            pv[2] = f2bf(acc[n][2]); pv[3] = f2bf(acc[n][3]);
            *(ushort4_t*)(vw + (size_t)bq * 64 * 2048 + (size_t)col * 2048 + sl) = pv;
        }
    }
}

// ---------------- Kernel 2: flash attention v2 ----------------
// 1 wave = 1 job = 32 q-rows x NKT*64 keys. 32x32x16 MFMA, swapped operands,
// in-register softmax, K/V fragments direct from L2 (no LDS/barriers in loop).
// mbuf is stored in SCALED-logit domain (m*0.125) so combine's e^dm is right.
template<int NKT>
__global__ __launch_bounds__(256, 2) void attn_kernel(const unsigned short* __restrict__ qw,
                                                      const unsigned short* __restrict__ kw,
                                                      const unsigned short* __restrict__ vw,
                                                      float* __restrict__ Op,
                                                      float* __restrict__ mbuf,
                                                      float* __restrict__ lbuf) {
    __shared__ float tl[4][2048];  // per-wave 8KB O-transpose buffer
    const float C = 0.18033688f;   // 0.125 * log2(e)

    int t = threadIdx.x, lane = t & 63, w = t >> 6;
    int q31 = lane & 31, Hh = lane >> 5;
    int b = blockIdx.y;
    int sp = blockIdx.z;
    int qt = blockIdx.x * 4 + w;
    int q0 = qt * 32;
    int key00 = sp * NKT * 64;

    const unsigned short* Kb = kw + (size_t)b * 2048 * 64;
    const unsigned short* Vb = vw + (size_t)b * 64 * 2048;

    // Q fragments: B-operand, col=q=lane&31, k-slot (e,Hh) <-> d = ks*16 + e + 8*Hh
    bf16x8 Qf[4];
    {
        const unsigned short* Qr = qw + ((size_t)b * 2048 + q0 + q31) * 64 + Hh * 8;
#pragma unroll
        for (int ks = 0; ks < 4; ++ks) Qf[ks] = *(const bf16x8*)(Qr + ks * 16);
    }

    f32x16 Of0, Of1;
#pragma unroll
    for (int j = 0; j < 16; ++j) { Of0[j] = 0.f; Of1[j] = 0.f; }
    float m_run = -INFINITY, l_run = 0.f;

    bf16x8 ka[2][2][4], vf[2][2][4];
    // prologue loads (tile 0)
#pragma unroll
    for (int kb = 0; kb < 2; ++kb)
#pragma unroll
        for (int ks = 0; ks < 4; ++ks)
            ka[0][kb][ks] = *(const bf16x8*)(Kb + (size_t)(key00 + kb * 32 + q31) * 64 + ks * 16 + Hh * 8);
#pragma unroll
    for (int db = 0; db < 2; ++db)
#pragma unroll
        for (int ks = 0; ks < 4; ++ks)
            vf[0][db][ks] = *(const bf16x8*)(Vb + (size_t)(db * 32 + q31) * 2048 + key00 + ks * 16 + Hh * 8);

#pragma unroll
    for (int kt = 0; kt < NKT; ++kt) {
        int cb = kt & 1;
        if (kt < NKT - 1) {
            int kbase = key00 + (kt + 1) * 64;
#pragma unroll
            for (int kb = 0; kb < 2; ++kb)
#pragma unroll
                for (int ks = 0; ks < 4; ++ks)
                    ka[cb ^ 1][kb][ks] = *(const bf16x8*)(Kb + (size_t)(kbase + kb * 32 + q31) * 64 + ks * 16 + Hh * 8);
#pragma unroll
            for (int db = 0; db < 2; ++db)
#pragma unroll
                for (int ks = 0; ks < 4; ++ks)
                    vf[cb ^ 1][db][ks] = *(const bf16x8*)(Vb + (size_t)(db * 32 + q31) * 2048 + kbase + ks * 16 + Hh * 8);
        }

        // QK^T swapped: D[key][q], A=K, B=Q
        f32x16 z0, z1;
#pragma unroll
        for (int j = 0; j < 16; ++j) { z0[j] = 0.f; z1[j] = 0.f; }
#pragma unroll
        for (int ks = 0; ks < 4; ++ks) {
            z0 = __builtin_amdgcn_mfma_f32_32x32x16_bf16(ka[cb][0][ks], Qf[ks], z0, 0, 0, 0);
            z1 = __builtin_amdgcn_mfma_f32_32x32x16_bf16(ka[cb][1][ks], Qf[ks], z1, 0, 0, 0);
        }

        // online softmax, lane-local (q = lane&31); raw-domain max
        float mx = fmaxf(z0[0], z1[0]);
#pragma unroll
        for (int j = 1; j < 16; ++j) mx = fmaxf(mx, fmaxf(z0[j], z1[j]));
        mx = fmaxf(mx, __shfl_xor(mx, 32));
        float m_new = fmaxf(m_run, mx);
        float mzc = m_new * C;
        float alpha = exp2f((m_run - m_new) * C);
        m_run = m_new;

        float p[32];
#pragma unroll
        for (int j = 0; j < 16; ++j) {
            p[j] = exp2f(z0[j] * C - mzc);
            p[16 + j] = exp2f(z1[j] * C - mzc);
        }
        float ls = 0.f;
#pragma unroll
        for (int j = 0; j < 32; ++j) ls += p[j];
        l_run = l_run * alpha + ls;
        Of0 *= alpha;
        Of1 *= alpha;

        // pack P -> bf16 B-fragments (col=q). slot(e,Hh) <-> key = ks*16 + e + 8*Hh
        bf16x8 pa[4];
#pragma unroll
        for (int tt = 0; tt < 2; ++tt) {
#pragma unroll
            for (int k2 = 0; k2 < 2; ++k2) {
                int base = tt * 16 + k2 * 8;
                unsigned int wA = pkbf(p[base + 0], p[base + 1]);
                unsigned int wA2 = pkbf(p[base + 2], p[base + 3]);
                unsigned int wB = pkbf(p[base + 4], p[base + 5]);
                unsigned int wB2 = pkbf(p[base + 6], p[base + 7]);
                unsigned int s0 = Hh ? wA : wB, s1 = Hh ? wA2 : wB2;
                unsigned int k0 = Hh ? wB : wA, k1 = Hh ? wB2 : wA2;
                unsigned int r0 = (unsigned int)__shfl_xor((int)s0, 32);
                unsigned int r1 = (unsigned int)__shfl_xor((int)s1, 32);
                u32x4 fw;
                fw[0] = Hh ? r0 : k0;
                fw[1] = Hh ? r1 : k1;
                fw[2] = Hh ? k0 : r0;
                fw[3] = Hh ? k1 : r1;
                pa[tt * 2 + k2] = __builtin_bit_cast(bf16x8, fw);
            }
        }

        // PV swapped: D[d][q], A=V^T, B=P
#pragma unroll
        for (int ks = 0; ks < 4; ++ks) {
            Of0 = __builtin_amdgcn_mfma_f32_32x32x16_bf16(vf[cb][0][ks], pa[ks], Of0, 0, 0, 0);
            Of1 = __builtin_amdgcn_mfma_f32_32x32x16_bf16(vf[cb][1][ks], pa[ks], Of1, 0, 0, 0);
        }
    }

    // write partial m (SCALED domain = m*0.125), l
    float l_tot = l_run + __shfl_xor(l_run, 32);
    size_t rowbase = (size_t)sp * 16384 + b * 2048 + q0;
    if (Hh == 0) {
        mbuf[rowbase + q31] = m_run * 0.125f;
        lbuf[rowbase + q31] = l_tot;
    }

    // O transpose via per-wave LDS (rotated to avoid bank conflicts), then
    // coalesced Op write. Of tile rows d = db*32 + (r&3)+8*(r>>2)+4*Hh, col q.
    float* tw = tl[w];
#pragma unroll
    for (int r = 0; r < 16; ++r) {
        int d0 = (r & 3) + 8 * (r >> 2) + 4 * Hh;
        tw[q31 * 64 + ((d0 + q31) & 63)] = Of0[r];
        int d1 = 32 + d0;
        tw[q31 * 64 + ((d1 + q31) & 63)] = Of1[r];
    }
    __syncthreads();
    {
        int qr = lane >> 1, half = lane & 1;
        float v[32];
#pragma unroll
        for (int j = 0; j < 32; ++j) {
            int d = half * 32 + j;
            v[j] = tw[qr * 64 + ((d + qr) & 63)];
        }
        float* dst = Op + (rowbase + qr) * 64 + half * 32;
#pragma unroll
        for (int c = 0; c < 8; ++c) {
            f32x4 vv = {v[4 * c], v[4 * c + 1], v[4 * c + 2], v[4 * c + 3]};
            *(f32x4*)(dst + 4 * c) = vv;
        }
    }
}

// ---------------- Kernel 3: split combine ----------------
__global__ __launch_bounds__(256) void combine_kernel(const float* __restrict__ Op,
                                                      const float* __restrict__ mbuf,
                                                      const float* __restrict__ lbuf,
                                                      float* __restrict__ out,
                                                      int nsplit) {
    int row = blockIdx.x * 4 + (threadIdx.x >> 6);
    int col = threadIdx.x & 63;
    float M = -INFINITY;
    for (int s = 0; s < nsplit; ++s) M = fmaxf(M, mbuf[s * 16384 + row]);
    float L = 0.f, acc = 0.f;
    for (int s = 0; s < nsplit; ++s) {
        float wgt = exp2f((mbuf[s * 16384 + row] - M) * 1.44269504f);
        L += lbuf[s * 16384 + row] * wgt;
        acc += Op[((size_t)s * 16384 + row) * 64 + col] * wgt;
    }
    out[(size_t)row * 64 + col] = acc / L;
}

extern "C" void kernel_launch(void* const* d_in, const int* in_sizes, int n_in,
                              void* d_out, int out_size, void* d_ws, size_t ws_size,
                              hipStream_t stream) {
    const float* x  = (const float*)d_in[0];
    const float* Wq = (const float*)d_in[1];
    const float* Wk = (const float*)d_in[2];
    const float* Wv = (const float*)d_in[3];
    char* ws = (char*)d_ws;
    unsigned short* Wt = (unsigned short*)ws;                       // 384KB
    unsigned short* qw = (unsigned short*)(ws + 393216);            // 2MB
    unsigned short* kw = (unsigned short*)(ws + 393216 + 2097152);  // 2MB
    unsigned short* vw = (unsigned short*)(ws + 393216 + 4194304);  // 2MB
    float* out = (float*)d_out;

    const size_t base = 393216 + 3 * 2097152;  // 6684672
    const size_t per_split = 16384ULL * 64 * 4 + 2 * 16384ULL * 4;  // Op + m + l
    int nsplit = 1;
    if (ws_size >= base + 4 * per_split) nsplit = 4;
    else if (ws_size >= base + 2 * per_split) nsplit = 2;

    float* Op   = (float*)(ws + base);
    float* mbuf = (float*)(ws + base + (size_t)nsplit * 16384 * 64 * 4);
    float* lbuf = mbuf + (size_t)nsplit * 16384;

    hipLaunchKernelGGL(prep_w_kernel, dim3(16, 3), dim3(256), 0, stream, Wq, Wk, Wv, Wt);
    hipLaunchKernelGGL(qkv_kernel, dim3(512), dim3(256), 0, stream, x, Wt, qw, kw, vw);
    if (nsplit == 4)
        hipLaunchKernelGGL(attn_kernel<8>, dim3(16, 8, 4), dim3(256), 0, stream, qw, kw, vw, Op, mbuf, lbuf);
    else if (nsplit == 2)
        hipLaunchKernelGGL(attn_kernel<16>, dim3(16, 8, 2), dim3(256), 0, stream, qw, kw, vw, Op, mbuf, lbuf);
    else
        hipLaunchKernelGGL(attn_kernel<32>, dim3(16, 8, 1), dim3(256), 0, stream, qw, kw, vw, Op, mbuf, lbuf);
    hipLaunchKernelGGL(combine_kernel, dim3(4096), dim3(256), 0, stream, Op, mbuf, lbuf, out, nsplit);
}

// Round 7
// 67.656 us; speedup vs baseline: 1.1178x; 1.1178x over previous
//
#include <hip/hip_runtime.h>
#include <hip/hip_bf16.h>
#include <math.h>

typedef float f32x4 __attribute__((ext_vector_type(4)));
typedef float f32x16 __attribute__((ext_vector_type(16)));
typedef __bf16 bf16x8 __attribute__((ext_vector_type(8)));
typedef unsigned short ushort4_t __attribute__((ext_vector_type(4)));
typedef unsigned int u32x4 __attribute__((ext_vector_type(4)));

#define B_ 8
#define S_ 2048
#define D_ 1024
#define H_ 64

static __device__ __forceinline__ unsigned short f2bf(float f) {
    __bf16 h = (__bf16)f;
    return __builtin_bit_cast(unsigned short, h);
}
static __device__ __forceinline__ unsigned int pkbf(float lo, float hi) {
    return ((unsigned int)f2bf(hi) << 16) | (unsigned int)f2bf(lo);
}

static __device__ __forceinline__ void gload16(const void* g, void* l) {
    __builtin_amdgcn_global_load_lds(
        (__attribute__((address_space(1))) void*)(void*)g,
        (__attribute__((address_space(3))) void*)l, 16, 0, 0);
}

// Stage a contiguous 8KB global region into LDS with inverse-swizzled SOURCE so
// that reads with byte ^ ((row&7)<<4) (row = byte>>7, 128B rows) see logical data.
static __device__ __forceinline__ void stage_contig(const char* gsrc, char* dst, int w, int lane) {
#pragma unroll
    for (int i = 0; i < 2; ++i) {
        int ch = w * 128 + i * 64 + lane;
        int p = ch * 16;
        int so = p ^ (((p >> 7) & 7) << 4);
        gload16(gsrc + so, dst + (w * 128 + i * 64) * 16);
    }
}

// Stage a [64 rows][128B] tile whose global rows are strided (vT: 4096B stride).
static __device__ __forceinline__ void stage_v(const unsigned short* Vb, int k0, char* dst, int w, int lane) {
#pragma unroll
    for (int i = 0; i < 2; ++i) {
        int ch = w * 128 + i * 64 + lane;
        int p = ch * 16;
        int rr = p >> 7;
        int off = (p ^ ((rr & 7) << 4)) & 127;
        const char* gsrc = (const char*)(Vb + (size_t)rr * 2048 + k0) + off;
        gload16(gsrc, dst + (w * 128 + i * 64) * 16);
    }
}

// Stage Wt tile: 192 rows x 128B, global row stride 2048B. 1536 chunks, 6 per wave-lane.
static __device__ __forceinline__ void stage_wt(const unsigned short* Wt, int kt, char* dst, int w, int lane) {
#pragma unroll
    for (int i = 0; i < 6; ++i) {
        int ch = w * 384 + i * 64 + lane;
        int p = ch * 16;
        int rr = p >> 7;
        int off = (p ^ ((rr & 7) << 4)) & 127;
        const char* gsrc = (const char*)Wt + (size_t)rr * 2048 + kt * 128 + off;
        gload16(gsrc, dst + (w * 384 + i * 64) * 16);
    }
}

// ---------------- Kernel 0: W [1024][64] f32 -> Wt [3][64][1024] bf16 ----------------
__global__ __launch_bounds__(256) void prep_w_kernel(const float* __restrict__ Wq,
                                                     const float* __restrict__ Wk,
                                                     const float* __restrict__ Wv,
                                                     unsigned short* __restrict__ Wt) {
    __shared__ float tile[64][65];
    int which = blockIdx.y;
    const float* W = (which == 0) ? Wq : ((which == 1) ? Wk : Wv);
    int k0 = blockIdx.x * 64;
    int t = threadIdx.x;
    int r = t >> 2, c0 = (t & 3) * 16;
#pragma unroll
    for (int j = 0; j < 16; ++j) tile[r][c0 + j] = W[(size_t)(k0 + r) * 64 + c0 + j];
    __syncthreads();
    unsigned short* dst = Wt + (size_t)(which * 64 + r) * 1024 + k0 + c0;
#pragma unroll
    for (int j = 0; j < 16; ++j) dst[j] = f2bf(tile[c0 + j][r]);
}

// ---------------- Kernel 1: qkv projection, 32-row M-tiles ----------------
__global__ __launch_bounds__(256) void qkv_kernel(const float* __restrict__ x,
                                                  const unsigned short* __restrict__ Wt,
                                                  unsigned short* __restrict__ qw,
                                                  unsigned short* __restrict__ kw,
                                                  unsigned short* __restrict__ vw) {
    __shared__ __align__(16) char lds[4096 + 2 * 24576];
    char* xs = lds;
    int t = threadIdx.x, lane = t & 63, w = t >> 6, g = lane >> 4, qi = lane & 15;
    int m0 = blockIdx.x * 32;
    int row = t >> 3, seg = t & 7;
    const float* xrow = x + (size_t)(m0 + row) * 1024 + seg * 8;

    f32x4 acc[6];
#pragma unroll
    for (int n = 0; n < 6; ++n) acc[n] = (f32x4){0.f, 0.f, 0.f, 0.f};

    float4 xr0 = *(const float4*)(xrow + 0);
    float4 xr1 = *(const float4*)(xrow + 4);
    stage_wt(Wt, 0, lds + 4096, w, lane);

    int rh = w & 1, ch = w >> 1;
    int cur = 0;
    for (int kt = 0; kt < 16; ++kt) {
        bf16x8 pk;
        pk[0] = (__bf16)xr0.x; pk[1] = (__bf16)xr0.y; pk[2] = (__bf16)xr0.z; pk[3] = (__bf16)xr0.w;
        pk[4] = (__bf16)xr1.x; pk[5] = (__bf16)xr1.y; pk[6] = (__bf16)xr1.z; pk[7] = (__bf16)xr1.w;
        int b0 = row * 128 + seg * 16;
        *(bf16x8*)(xs + (b0 ^ ((row & 7) << 4))) = pk;
        __syncthreads();

        if (kt < 15) {
            const float* nsrc = xrow + (kt + 1) * 64;
            xr0 = *(const float4*)(nsrc + 0);
            xr1 = *(const float4*)(nsrc + 4);
            stage_wt(Wt, kt + 1, lds + 4096 + (cur ^ 1) * 24576, w, lane);
        }
        const char* wsb = lds + 4096 + cur * 24576;

        int arow = rh * 16 + qi;
        int swa = (arow & 7) << 4;
#pragma unroll
        for (int ks = 0; ks < 2; ++ks) {
            bf16x8 a = *(const bf16x8*)(xs + ((arow * 128 + ks * 64 + g * 16) ^ swa));
#pragma unroll
            for (int n = 0; n < 6; ++n) {
                int brow = ch * 96 + n * 16 + qi;
                bf16x8 bb = *(const bf16x8*)(wsb + ((brow * 128 + ks * 64 + g * 16) ^ ((brow & 7) << 4)));
                acc[n] = __builtin_amdgcn_mfma_f32_16x16x32_bf16(a, bb, acc[n], 0, 0, 0);
            }
        }
        __syncthreads();
        cur ^= 1;
    }

    int bq = m0 >> 11;
    int sl = (m0 & 2047) + rh * 16 + g * 4;
    int rowg = m0 + rh * 16 + g * 4;
#pragma unroll
    for (int n = 0; n < 6; ++n) {
        int c = ch * 96 + n * 16;
        int which = c >> 6;
        int col = (c & 63) + qi;
        if (which == 0) {
#pragma unroll
            for (int r = 0; r < 4; ++r)
                qw[(size_t)(rowg + r) * 64 + col] = f2bf(acc[n][r]);
        } else if (which == 1) {
#pragma unroll
            for (int r = 0; r < 4; ++r)
                kw[(size_t)(rowg + r) * 64 + col] = f2bf(acc[n][r]);
        } else {
            ushort4_t pv;
            pv[0] = f2bf(acc[n][0]); pv[1] = f2bf(acc[n][1]);
            pv[2] = f2bf(acc[n][2]); pv[3] = f2bf(acc[n][3]);
            *(ushort4_t*)(vw + (size_t)bq * 64 * 2048 + (size_t)col * 2048 + sl) = pv;
        }
    }
}

// ---------------- Kernel 2: flash attention v3 ----------------
// 1 wave = 32 q-rows x NKT*64 keys; 4 waves/block share the K/V slice.
// K/V staged in block-shared LDS (XOR-swizzled, double-buffered, 32KB);
// 32x32x16 MFMA swapped both ways; softmax + P-pack fully in-register.
// mbuf stored in SCALED-logit domain (m*0.125).
// LDS: K dbuf [0,16384), V dbuf [16384,32768); epilogue reuses [w*8192, +8KB).
template<int NKT>
__global__ __launch_bounds__(256, 4) void attn_kernel(const unsigned short* __restrict__ qw,
                                                      const unsigned short* __restrict__ kw,
                                                      const unsigned short* __restrict__ vw,
                                                      float* __restrict__ Op,
                                                      float* __restrict__ mbuf,
                                                      float* __restrict__ lbuf) {
    __shared__ __align__(16) char lds[32768];
    const float C = 0.18033688f;   // 0.125 * log2(e)

    int t = threadIdx.x, lane = t & 63, w = t >> 6;
    int q31 = lane & 31, Hh = lane >> 5;
    int b = blockIdx.y;
    int sp = blockIdx.z;
    int qt = blockIdx.x * 4 + w;
    int q0 = qt * 32;
    int key00 = sp * NKT * 64;

    const unsigned short* Kb = kw + (size_t)b * 2048 * 64;
    const unsigned short* Vb = vw + (size_t)b * 64 * 2048;

    // Q fragments: B-operand, col=q=lane&31, k-slot (e,Hh) <-> d = ks*16 + e + 8*Hh
    bf16x8 Qf[4];
    {
        const unsigned short* Qr = qw + ((size_t)b * 2048 + q0 + q31) * 64 + Hh * 8;
#pragma unroll
        for (int ks = 0; ks < 4; ++ks) Qf[ks] = *(const bf16x8*)(Qr + ks * 16);
    }

    // prologue: stage tile 0
    stage_contig((const char*)(Kb + (size_t)key00 * 64), lds, w, lane);
    stage_v(Vb, key00, lds + 16384, w, lane);

    f32x16 Of0, Of1;
#pragma unroll
    for (int j = 0; j < 16; ++j) { Of0[j] = 0.f; Of1[j] = 0.f; }
    float m_run = -INFINITY, l_run = 0.f;

    int swk0 = (q31 & 7) << 4;           // rows q31 and 32+q31 share (row&7)
    __syncthreads();

    int cur = 0;
    for (int kt = 0; kt < NKT; ++kt) {
        if (kt + 1 < NKT) {
            int knext = key00 + (kt + 1) * 64;
            stage_contig((const char*)(Kb + (size_t)knext * 64), lds + (cur ^ 1) * 8192, w, lane);
            stage_v(Vb, knext, lds + 16384 + (cur ^ 1) * 8192, w, lane);
        }
        const char* Kt_ = lds + cur * 8192;
        const char* Vt_ = lds + 16384 + cur * 8192;

        // QK^T swapped: D[key][q], A=K rows (from LDS), B=Q
        f32x16 z0, z1;
#pragma unroll
        for (int j = 0; j < 16; ++j) { z0[j] = 0.f; z1[j] = 0.f; }
        __builtin_amdgcn_s_setprio(1);
#pragma unroll
        for (int ks = 0; ks < 4; ++ks) {
            bf16x8 ka0 = *(const bf16x8*)(Kt_ + ((q31 * 128 + ks * 32 + Hh * 16) ^ swk0));
            bf16x8 ka1 = *(const bf16x8*)(Kt_ + (((32 + q31) * 128 + ks * 32 + Hh * 16) ^ swk0));
            z0 = __builtin_amdgcn_mfma_f32_32x32x16_bf16(ka0, Qf[ks], z0, 0, 0, 0);
            z1 = __builtin_amdgcn_mfma_f32_32x32x16_bf16(ka1, Qf[ks], z1, 0, 0, 0);
        }
        __builtin_amdgcn_s_setprio(0);

        // online softmax, lane-local (q = lane&31); raw-domain max
        float mx = fmaxf(z0[0], z1[0]);
#pragma unroll
        for (int j = 1; j < 16; ++j) mx = fmaxf(mx, fmaxf(z0[j], z1[j]));
        mx = fmaxf(mx, __shfl_xor(mx, 32));
        float m_new = fmaxf(m_run, mx);
        float mzc = m_new * C;
        float alpha = exp2f((m_run - m_new) * C);
        m_run = m_new;

        float p[32];
#pragma unroll
        for (int j = 0; j < 16; ++j) {
            p[j] = exp2f(z0[j] * C - mzc);
            p[16 + j] = exp2f(z1[j] * C - mzc);
        }
        float ls = 0.f;
#pragma unroll
        for (int j = 0; j < 32; ++j) ls += p[j];
        l_run = l_run * alpha + ls;
        Of0 *= alpha;
        Of1 *= alpha;

        // pack P -> bf16 B-fragments (col=q). slot(e,Hh) <-> key = ks*16 + e + 8*Hh
        bf16x8 pa[4];
#pragma unroll
        for (int tt = 0; tt < 2; ++tt) {
#pragma unroll
            for (int k2 = 0; k2 < 2; ++k2) {
                int base = tt * 16 + k2 * 8;
                unsigned int wA = pkbf(p[base + 0], p[base + 1]);
                unsigned int wA2 = pkbf(p[base + 2], p[base + 3]);
                unsigned int wB = pkbf(p[base + 4], p[base + 5]);
                unsigned int wB2 = pkbf(p[base + 6], p[base + 7]);
                unsigned int s0 = Hh ? wA : wB, s1 = Hh ? wA2 : wB2;
                unsigned int k0 = Hh ? wB : wA, k1 = Hh ? wB2 : wA2;
                unsigned int r0 = (unsigned int)__shfl_xor((int)s0, 32);
                unsigned int r1 = (unsigned int)__shfl_xor((int)s1, 32);
                u32x4 fw;
                fw[0] = Hh ? r0 : k0;
                fw[1] = Hh ? r1 : k1;
                fw[2] = Hh ? k0 : r0;
                fw[3] = Hh ? k1 : r1;
                pa[tt * 2 + k2] = __builtin_bit_cast(bf16x8, fw);
            }
        }

        // PV swapped: D[d][q], A=V^T rows (from LDS), B=P
        __builtin_amdgcn_s_setprio(1);
#pragma unroll
        for (int ks = 0; ks < 4; ++ks) {
            bf16x8 vf0 = *(const bf16x8*)(Vt_ + ((q31 * 128 + ks * 32 + Hh * 16) ^ swk0));
            bf16x8 vf1 = *(const bf16x8*)(Vt_ + (((32 + q31) * 128 + ks * 32 + Hh * 16) ^ swk0));
            Of0 = __builtin_amdgcn_mfma_f32_32x32x16_bf16(vf0, pa[ks], Of0, 0, 0, 0);
            Of1 = __builtin_amdgcn_mfma_f32_32x32x16_bf16(vf1, pa[ks], Of1, 0, 0, 0);
        }
        __builtin_amdgcn_s_setprio(0);
        __syncthreads();
        cur ^= 1;
    }

    // write partial m (SCALED domain = m*0.125), l
    float l_tot = l_run + __shfl_xor(l_run, 32);
    size_t rowbase = (size_t)sp * 16384 + b * 2048 + q0;
    if (Hh == 0) {
        mbuf[rowbase + q31] = m_run * 0.125f;
        lbuf[rowbase + q31] = l_tot;
    }

    // O transpose via per-wave LDS chunk (reuse dead K/V space), rotated to
    // avoid bank conflicts, then coalesced Op write.
    float* tw = (float*)(lds + w * 8192);
#pragma unroll
    for (int r = 0; r < 16; ++r) {
        int d0 = (r & 3) + 8 * (r >> 2) + 4 * Hh;
        tw[q31 * 64 + ((d0 + q31) & 63)] = Of0[r];
        int d1 = 32 + d0;
        tw[q31 * 64 + ((d1 + q31) & 63)] = Of1[r];
    }
    __syncthreads();
    {
        int qr = lane >> 1, half = lane & 1;
        float v[32];
#pragma unroll
        for (int j = 0; j < 32; ++j) {
            int d = half * 32 + j;
            v[j] = tw[qr * 64 + ((d + qr) & 63)];
        }
        float* dst = Op + (rowbase + qr) * 64 + half * 32;
#pragma unroll
        for (int c = 0; c < 8; ++c) {
            f32x4 vv = {v[4 * c], v[4 * c + 1], v[4 * c + 2], v[4 * c + 3]};
            *(f32x4*)(dst + 4 * c) = vv;
        }
    }
}

// ---------------- Kernel 3: split combine ----------------
__global__ __launch_bounds__(256) void combine_kernel(const float* __restrict__ Op,
                                                      const float* __restrict__ mbuf,
                                                      const float* __restrict__ lbuf,
                                                      float* __restrict__ out,
                                                      int nsplit) {
    int row = blockIdx.x * 4 + (threadIdx.x >> 6);
    int col = threadIdx.x & 63;
    float M = -INFINITY;
    for (int s = 0; s < nsplit; ++s) M = fmaxf(M, mbuf[s * 16384 + row]);
    float L = 0.f, acc = 0.f;
    for (int s = 0; s < nsplit; ++s) {
        float wgt = exp2f((mbuf[s * 16384 + row] - M) * 1.44269504f);
        L += lbuf[s * 16384 + row] * wgt;
        acc += Op[((size_t)s * 16384 + row) * 64 + col] * wgt;
    }
    out[(size_t)row * 64 + col] = acc / L;
}

extern "C" void kernel_launch(void* const* d_in, const int* in_sizes, int n_in,
                              void* d_out, int out_size, void* d_ws, size_t ws_size,
                              hipStream_t stream) {
    const float* x  = (const float*)d_in[0];
    const float* Wq = (const float*)d_in[1];
    const float* Wk = (const float*)d_in[2];
    const float* Wv = (const float*)d_in[3];
    char* ws = (char*)d_ws;
    unsigned short* Wt = (unsigned short*)ws;                       // 384KB
    unsigned short* qw = (unsigned short*)(ws + 393216);            // 2MB
    unsigned short* kw = (unsigned short*)(ws + 393216 + 2097152);  // 2MB
    unsigned short* vw = (unsigned short*)(ws + 393216 + 4194304);  // 2MB
    float* out = (float*)d_out;

    const size_t base = 393216 + 3 * 2097152;  // 6684672
    const size_t per_split = 16384ULL * 64 * 4 + 2 * 16384ULL * 4;  // Op + m + l
    int nsplit = 1;
    if (ws_size >= base + 8 * per_split) nsplit = 8;
    else if (ws_size >= base + 4 * per_split) nsplit = 4;
    else if (ws_size >= base + 2 * per_split) nsplit = 2;

    float* Op   = (float*)(ws + base);
    float* mbuf = (float*)(ws + base + (size_t)nsplit * 16384 * 64 * 4);
    float* lbuf = mbuf + (size_t)nsplit * 16384;

    hipLaunchKernelGGL(prep_w_kernel, dim3(16, 3), dim3(256), 0, stream, Wq, Wk, Wv, Wt);
    hipLaunchKernelGGL(qkv_kernel, dim3(512), dim3(256), 0, stream, x, Wt, qw, kw, vw);
    if (nsplit == 8)
        hipLaunchKernelGGL(attn_kernel<4>, dim3(16, 8, 8), dim3(256), 0, stream, qw, kw, vw, Op, mbuf, lbuf);
    else if (nsplit == 4)
        hipLaunchKernelGGL(attn_kernel<8>, dim3(16, 8, 4), dim3(256), 0, stream, qw, kw, vw, Op, mbuf, lbuf);
    else if (nsplit == 2)
        hipLaunchKernelGGL(attn_kernel<16>, dim3(16, 8, 2), dim3(256), 0, stream, qw, kw, vw, Op, mbuf, lbuf);
    else
        hipLaunchKernelGGL(attn_kernel<32>, dim3(16, 8, 1), dim3(256), 0, stream, qw, kw, vw, Op, mbuf, lbuf);
    hipLaunchKernelGGL(combine_kernel, dim3(4096), dim3(256), 0, stream, Op, mbuf, lbuf, out, nsplit);
}

// Round 8
// 67.423 us; speedup vs baseline: 1.1216x; 1.0035x over previous
//
#include <hip/hip_runtime.h>
#include <hip/hip_bf16.h>
#include <math.h>

typedef float f32x4 __attribute__((ext_vector_type(4)));
typedef float f32x16 __attribute__((ext_vector_type(16)));
typedef __bf16 bf16x8 __attribute__((ext_vector_type(8)));
typedef unsigned short ushort4_t __attribute__((ext_vector_type(4)));
typedef unsigned int u32x4 __attribute__((ext_vector_type(4)));

#define B_ 8
#define S_ 2048
#define D_ 1024
#define H_ 64

static __device__ __forceinline__ unsigned short f2bf(float f) {
    __bf16 h = (__bf16)f;
    return __builtin_bit_cast(unsigned short, h);
}
static __device__ __forceinline__ unsigned int pkbf(float lo, float hi) {
    return ((unsigned int)f2bf(hi) << 16) | (unsigned int)f2bf(lo);
}

static __device__ __forceinline__ void gload16(const void* g, void* l) {
    __builtin_amdgcn_global_load_lds(
        (__attribute__((address_space(1))) void*)(void*)g,
        (__attribute__((address_space(3))) void*)l, 16, 0, 0);
}

// Stage a contiguous 8KB global region into LDS with inverse-swizzled SOURCE so
// that reads with byte ^ ((row&7)<<4) (row = byte>>7, 128B rows) see logical data.
static __device__ __forceinline__ void stage_contig(const char* gsrc, char* dst, int w, int lane) {
#pragma unroll
    for (int i = 0; i < 2; ++i) {
        int ch = w * 128 + i * 64 + lane;
        int p = ch * 16;
        int so = p ^ (((p >> 7) & 7) << 4);
        gload16(gsrc + so, dst + (w * 128 + i * 64) * 16);
    }
}

// Stage a [64 rows][128B] tile whose global rows are strided (vT: 4096B stride).
static __device__ __forceinline__ void stage_v(const unsigned short* Vb, int k0, char* dst, int w, int lane) {
#pragma unroll
    for (int i = 0; i < 2; ++i) {
        int ch = w * 128 + i * 64 + lane;
        int p = ch * 16;
        int rr = p >> 7;
        int off = (p ^ ((rr & 7) << 4)) & 127;
        const char* gsrc = (const char*)(Vb + (size_t)rr * 2048 + k0) + off;
        gload16(gsrc, dst + (w * 128 + i * 64) * 16);
    }
}

// Stage Wt tile: 192 rows x 128B, global row stride 2048B. 1536 chunks, 6 per wave-lane.
static __device__ __forceinline__ void stage_wt(const unsigned short* Wt, int kt, char* dst, int w, int lane) {
#pragma unroll
    for (int i = 0; i < 6; ++i) {
        int ch = w * 384 + i * 64 + lane;
        int p = ch * 16;
        int rr = p >> 7;
        int off = (p ^ ((rr & 7) << 4)) & 127;
        const char* gsrc = (const char*)Wt + (size_t)rr * 2048 + kt * 128 + off;
        gload16(gsrc, dst + (w * 384 + i * 64) * 16);
    }
}

// ---------------- Kernel 0: W [1024][64] f32 -> Wt [3][64][1024] bf16 ----------------
__global__ __launch_bounds__(256) void prep_w_kernel(const float* __restrict__ Wq,
                                                     const float* __restrict__ Wk,
                                                     const float* __restrict__ Wv,
                                                     unsigned short* __restrict__ Wt) {
    __shared__ float tile[64][65];
    int which = blockIdx.y;
    const float* W = (which == 0) ? Wq : ((which == 1) ? Wk : Wv);
    int k0 = blockIdx.x * 64;
    int t = threadIdx.x;
    int r = t >> 2, c0 = (t & 3) * 16;
#pragma unroll
    for (int j = 0; j < 16; ++j) tile[r][c0 + j] = W[(size_t)(k0 + r) * 64 + c0 + j];
    __syncthreads();
    unsigned short* dst = Wt + (size_t)(which * 64 + r) * 1024 + k0 + c0;
#pragma unroll
    for (int j = 0; j < 16; ++j) dst[j] = f2bf(tile[c0 + j][r]);
}

// ---------------- Kernel 1: qkv projection, 32-row M-tiles ----------------
__global__ __launch_bounds__(256) void qkv_kernel(const float* __restrict__ x,
                                                  const unsigned short* __restrict__ Wt,
                                                  unsigned short* __restrict__ qw,
                                                  unsigned short* __restrict__ kw,
                                                  unsigned short* __restrict__ vw) {
    __shared__ __align__(16) char lds[4096 + 2 * 24576];
    char* xs = lds;
    int t = threadIdx.x, lane = t & 63, w = t >> 6, g = lane >> 4, qi = lane & 15;
    int m0 = blockIdx.x * 32;
    int row = t >> 3, seg = t & 7;
    const float* xrow = x + (size_t)(m0 + row) * 1024 + seg * 8;

    f32x4 acc[6];
#pragma unroll
    for (int n = 0; n < 6; ++n) acc[n] = (f32x4){0.f, 0.f, 0.f, 0.f};

    float4 xr0 = *(const float4*)(xrow + 0);
    float4 xr1 = *(const float4*)(xrow + 4);
    stage_wt(Wt, 0, lds + 4096, w, lane);

    int rh = w & 1, ch = w >> 1;
    int cur = 0;
    for (int kt = 0; kt < 16; ++kt) {
        bf16x8 pk;
        pk[0] = (__bf16)xr0.x; pk[1] = (__bf16)xr0.y; pk[2] = (__bf16)xr0.z; pk[3] = (__bf16)xr0.w;
        pk[4] = (__bf16)xr1.x; pk[5] = (__bf16)xr1.y; pk[6] = (__bf16)xr1.z; pk[7] = (__bf16)xr1.w;
        int b0 = row * 128 + seg * 16;
        *(bf16x8*)(xs + (b0 ^ ((row & 7) << 4))) = pk;
        __syncthreads();

        if (kt < 15) {
            const float* nsrc = xrow + (kt + 1) * 64;
            xr0 = *(const float4*)(nsrc + 0);
            xr1 = *(const float4*)(nsrc + 4);
            stage_wt(Wt, kt + 1, lds + 4096 + (cur ^ 1) * 24576, w, lane);
        }
        const char* wsb = lds + 4096 + cur * 24576;

        int arow = rh * 16 + qi;
        int swa = (arow & 7) << 4;
#pragma unroll
        for (int ks = 0; ks < 2; ++ks) {
            bf16x8 a = *(const bf16x8*)(xs + ((arow * 128 + ks * 64 + g * 16) ^ swa));
#pragma unroll
            for (int n = 0; n < 6; ++n) {
                int brow = ch * 96 + n * 16 + qi;
                bf16x8 bb = *(const bf16x8*)(wsb + ((brow * 128 + ks * 64 + g * 16) ^ ((brow & 7) << 4)));
                acc[n] = __builtin_amdgcn_mfma_f32_16x16x32_bf16(a, bb, acc[n], 0, 0, 0);
            }
        }
        __syncthreads();
        cur ^= 1;
    }

    int bq = m0 >> 11;
    int sl = (m0 & 2047) + rh * 16 + g * 4;
    int rowg = m0 + rh * 16 + g * 4;
#pragma unroll
    for (int n = 0; n < 6; ++n) {
        int c = ch * 96 + n * 16;
        int which = c >> 6;
        int col = (c & 63) + qi;
        if (which == 0) {
#pragma unroll
            for (int r = 0; r < 4; ++r)
                qw[(size_t)(rowg + r) * 64 + col] = f2bf(acc[n][r]);
        } else if (which == 1) {
#pragma unroll
            for (int r = 0; r < 4; ++r)
                kw[(size_t)(rowg + r) * 64 + col] = f2bf(acc[n][r]);
        } else {
            ushort4_t pv;
            pv[0] = f2bf(acc[n][0]); pv[1] = f2bf(acc[n][1]);
            pv[2] = f2bf(acc[n][2]); pv[3] = f2bf(acc[n][3]);
            *(ushort4_t*)(vw + (size_t)bq * 64 * 2048 + (size_t)col * 2048 + sl) = pv;
        }
    }
}

// pack 8 consecutive P values (already exp'd, living in z[OFF..OFF+7]) into a
// PV B-fragment: slot(e,Hh) <-> key = e + 8*Hh within this 16-key group's half.
template<int OFF>
static __device__ __forceinline__ bf16x8 pack_pa(const f32x16& z, int Hh) {
    unsigned int wA  = pkbf(z[OFF + 0], z[OFF + 1]);
    unsigned int wA2 = pkbf(z[OFF + 2], z[OFF + 3]);
    unsigned int wB  = pkbf(z[OFF + 4], z[OFF + 5]);
    unsigned int wB2 = pkbf(z[OFF + 6], z[OFF + 7]);
    unsigned int s0 = Hh ? wA : wB, s1 = Hh ? wA2 : wB2;
    unsigned int k0 = Hh ? wB : wA, k1 = Hh ? wB2 : wA2;
    unsigned int r0 = (unsigned int)__shfl_xor((int)s0, 32);
    unsigned int r1 = (unsigned int)__shfl_xor((int)s1, 32);
    u32x4 fw;
    fw[0] = Hh ? r0 : k0;
    fw[1] = Hh ? r1 : k1;
    fw[2] = Hh ? k0 : r0;
    fw[3] = Hh ? k1 : r1;
    return __builtin_bit_cast(bf16x8, fw);
}

// ---------------- Kernel 2: flash attention v3.1 ----------------
// 1 wave = 32 q-rows x NKT*64 keys; 4 waves/block share the K/V slice.
// K/V staged in block-shared LDS (XOR-swizzled, double-buffered, 32KB);
// 32x32x16 MFMA swapped both ways; softmax IN-PLACE in z regs (no p[32] --
// keeps peak live VGPRs ~110 < the 128 cap of launch_bounds(256,4)).
// mbuf stored in SCALED-logit domain (m*0.125).
template<int NKT>
__global__ __launch_bounds__(256, 4) void attn_kernel(const unsigned short* __restrict__ qw,
                                                      const unsigned short* __restrict__ kw,
                                                      const unsigned short* __restrict__ vw,
                                                      float* __restrict__ Op,
                                                      float* __restrict__ mbuf,
                                                      float* __restrict__ lbuf) {
    __shared__ __align__(16) char lds[32768];
    const float C = 0.18033688f;   // 0.125 * log2(e)

    int t = threadIdx.x, lane = t & 63, w = t >> 6;
    int q31 = lane & 31, Hh = lane >> 5;
    int b = blockIdx.y;
    int sp = blockIdx.z;
    int qt = blockIdx.x * 4 + w;
    int q0 = qt * 32;
    int key00 = sp * NKT * 64;

    const unsigned short* Kb = kw + (size_t)b * 2048 * 64;
    const unsigned short* Vb = vw + (size_t)b * 64 * 2048;

    // Q fragments: B-operand, col=q=lane&31, k-slot (e,Hh) <-> d = ks*16 + e + 8*Hh
    bf16x8 Qf[4];
    {
        const unsigned short* Qr = qw + ((size_t)b * 2048 + q0 + q31) * 64 + Hh * 8;
#pragma unroll
        for (int ks = 0; ks < 4; ++ks) Qf[ks] = *(const bf16x8*)(Qr + ks * 16);
    }

    // prologue: stage tile 0
    stage_contig((const char*)(Kb + (size_t)key00 * 64), lds, w, lane);
    stage_v(Vb, key00, lds + 16384, w, lane);

    f32x16 Of0, Of1;
#pragma unroll
    for (int j = 0; j < 16; ++j) { Of0[j] = 0.f; Of1[j] = 0.f; }
    float m_run = -INFINITY, l_run = 0.f;

    int swk0 = (q31 & 7) << 4;           // rows q31 and 32+q31 share (row&7)
    __syncthreads();

    int cur = 0;
#pragma unroll
    for (int kt = 0; kt < NKT; ++kt) {
        if (kt + 1 < NKT) {
            int knext = key00 + (kt + 1) * 64;
            stage_contig((const char*)(Kb + (size_t)knext * 64), lds + (cur ^ 1) * 8192, w, lane);
            stage_v(Vb, knext, lds + 16384 + (cur ^ 1) * 8192, w, lane);
        }
        const char* Kt_ = lds + cur * 8192;
        const char* Vt_ = lds + 16384 + cur * 8192;

        // QK^T swapped: D[key][q], A=K rows (from LDS), B=Q
        f32x16 z0, z1;
#pragma unroll
        for (int j = 0; j < 16; ++j) { z0[j] = 0.f; z1[j] = 0.f; }
        __builtin_amdgcn_s_setprio(1);
#pragma unroll
        for (int ks = 0; ks < 4; ++ks) {
            bf16x8 ka0 = *(const bf16x8*)(Kt_ + ((q31 * 128 + ks * 32 + Hh * 16) ^ swk0));
            bf16x8 ka1 = *(const bf16x8*)(Kt_ + (((32 + q31) * 128 + ks * 32 + Hh * 16) ^ swk0));
            z0 = __builtin_amdgcn_mfma_f32_32x32x16_bf16(ka0, Qf[ks], z0, 0, 0, 0);
            z1 = __builtin_amdgcn_mfma_f32_32x32x16_bf16(ka1, Qf[ks], z1, 0, 0, 0);
        }
        __builtin_amdgcn_s_setprio(0);

        // online softmax, lane-local (q = lane&31); raw-domain max; exp IN PLACE
        float mx = fmaxf(z0[0], z1[0]);
#pragma unroll
        for (int j = 1; j < 16; ++j) mx = fmaxf(mx, fmaxf(z0[j], z1[j]));
        mx = fmaxf(mx, __shfl_xor(mx, 32));
        float m_new = fmaxf(m_run, mx);
        float mzc = m_new * C;
        float alpha = exp2f((m_run - m_new) * C);
        m_run = m_new;

#pragma unroll
        for (int j = 0; j < 16; ++j) {
            z0[j] = exp2f(z0[j] * C - mzc);
            z1[j] = exp2f(z1[j] * C - mzc);
        }
        float ls = 0.f;
#pragma unroll
        for (int j = 0; j < 16; ++j) ls += z0[j] + z1[j];
        l_run = l_run * alpha + ls;
        Of0 *= alpha;
        Of1 *= alpha;

        // pack P -> bf16 B-fragments directly from z (keys 0-15 in z0, 16-31 in z1)
        bf16x8 pa0 = pack_pa<0>(z0, Hh);
        bf16x8 pa1 = pack_pa<8>(z0, Hh);
        bf16x8 pa2 = pack_pa<0>(z1, Hh);
        bf16x8 pa3 = pack_pa<8>(z1, Hh);

        // PV swapped: D[d][q], A=V^T rows (from LDS), B=P
        __builtin_amdgcn_s_setprio(1);
        {
            bf16x8 vf0 = *(const bf16x8*)(Vt_ + ((q31 * 128 + 0 * 32 + Hh * 16) ^ swk0));
            bf16x8 vf1 = *(const bf16x8*)(Vt_ + (((32 + q31) * 128 + 0 * 32 + Hh * 16) ^ swk0));
            Of0 = __builtin_amdgcn_mfma_f32_32x32x16_bf16(vf0, pa0, Of0, 0, 0, 0);
            Of1 = __builtin_amdgcn_mfma_f32_32x32x16_bf16(vf1, pa0, Of1, 0, 0, 0);
            vf0 = *(const bf16x8*)(Vt_ + ((q31 * 128 + 1 * 32 + Hh * 16) ^ swk0));
            vf1 = *(const bf16x8*)(Vt_ + (((32 + q31) * 128 + 1 * 32 + Hh * 16) ^ swk0));
            Of0 = __builtin_amdgcn_mfma_f32_32x32x16_bf16(vf0, pa1, Of0, 0, 0, 0);
            Of1 = __builtin_amdgcn_mfma_f32_32x32x16_bf16(vf1, pa1, Of1, 0, 0, 0);
            vf0 = *(const bf16x8*)(Vt_ + ((q31 * 128 + 2 * 32 + Hh * 16) ^ swk0));
            vf1 = *(const bf16x8*)(Vt_ + (((32 + q31) * 128 + 2 * 32 + Hh * 16) ^ swk0));
            Of0 = __builtin_amdgcn_mfma_f32_32x32x16_bf16(vf0, pa2, Of0, 0, 0, 0);
            Of1 = __builtin_amdgcn_mfma_f32_32x32x16_bf16(vf1, pa2, Of1, 0, 0, 0);
            vf0 = *(const bf16x8*)(Vt_ + ((q31 * 128 + 3 * 32 + Hh * 16) ^ swk0));
            vf1 = *(const bf16x8*)(Vt_ + (((32 + q31) * 128 + 3 * 32 + Hh * 16) ^ swk0));
            Of0 = __builtin_amdgcn_mfma_f32_32x32x16_bf16(vf0, pa3, Of0, 0, 0, 0);
            Of1 = __builtin_amdgcn_mfma_f32_32x32x16_bf16(vf1, pa3, Of1, 0, 0, 0);
        }
        __builtin_amdgcn_s_setprio(0);
        __syncthreads();
        cur ^= 1;
    }

    // write partial m (SCALED domain = m*0.125), l
    float l_tot = l_run + __shfl_xor(l_run, 32);
    size_t rowbase = (size_t)sp * 16384 + b * 2048 + q0;
    if (Hh == 0) {
        mbuf[rowbase + q31] = m_run * 0.125f;
        lbuf[rowbase + q31] = l_tot;
    }

    // O transpose via per-wave LDS chunk (reuse dead K/V space), rotated to
    // avoid bank conflicts, then coalesced Op write.
    float* tw = (float*)(lds + w * 8192);
#pragma unroll
    for (int r = 0; r < 16; ++r) {
        int d0 = (r & 3) + 8 * (r >> 2) + 4 * Hh;
        tw[q31 * 64 + ((d0 + q31) & 63)] = Of0[r];
        int d1 = 32 + d0;
        tw[q31 * 64 + ((d1 + q31) & 63)] = Of1[r];
    }
    __syncthreads();
    {
        int qr = lane >> 1, half = lane & 1;
        float v[32];
#pragma unroll
        for (int j = 0; j < 32; ++j) {
            int d = half * 32 + j;
            v[j] = tw[qr * 64 + ((d + qr) & 63)];
        }
        float* dst = Op + (rowbase + qr) * 64 + half * 32;
#pragma unroll
        for (int c = 0; c < 8; ++c) {
            f32x4 vv = {v[4 * c], v[4 * c + 1], v[4 * c + 2], v[4 * c + 3]};
            *(f32x4*)(dst + 4 * c) = vv;
        }
    }
}

// ---------------- Kernel 3: split combine ----------------
__global__ __launch_bounds__(256) void combine_kernel(const float* __restrict__ Op,
                                                      const float* __restrict__ mbuf,
                                                      const float* __restrict__ lbuf,
                                                      float* __restrict__ out,
                                                      int nsplit) {
    int row = blockIdx.x * 4 + (threadIdx.x >> 6);
    int col = threadIdx.x & 63;
    float M = -INFINITY;
    for (int s = 0; s < nsplit; ++s) M = fmaxf(M, mbuf[s * 16384 + row]);
    float L = 0.f, acc = 0.f;
    for (int s = 0; s < nsplit; ++s) {
        float wgt = exp2f((mbuf[s * 16384 + row] - M) * 1.44269504f);
        L += lbuf[s * 16384 + row] * wgt;
        acc += Op[((size_t)s * 16384 + row) * 64 + col] * wgt;
    }
    out[(size_t)row * 64 + col] = acc / L;
}

extern "C" void kernel_launch(void* const* d_in, const int* in_sizes, int n_in,
                              void* d_out, int out_size, void* d_ws, size_t ws_size,
                              hipStream_t stream) {
    const float* x  = (const float*)d_in[0];
    const float* Wq = (const float*)d_in[1];
    const float* Wk = (const float*)d_in[2];
    const float* Wv = (const float*)d_in[3];
    char* ws = (char*)d_ws;
    unsigned short* Wt = (unsigned short*)ws;                       // 384KB
    unsigned short* qw = (unsigned short*)(ws + 393216);            // 2MB
    unsigned short* kw = (unsigned short*)(ws + 393216 + 2097152);  // 2MB
    unsigned short* vw = (unsigned short*)(ws + 393216 + 4194304);  // 2MB
    float* out = (float*)d_out;

    const size_t base = 393216 + 3 * 2097152;  // 6684672
    const size_t per_split = 16384ULL * 64 * 4 + 2 * 16384ULL * 4;  // Op + m + l
    int nsplit = 1;
    if (ws_size >= base + 8 * per_split) nsplit = 8;
    else if (ws_size >= base + 4 * per_split) nsplit = 4;
    else if (ws_size >= base + 2 * per_split) nsplit = 2;

    float* Op   = (float*)(ws + base);
    float* mbuf = (float*)(ws + base + (size_t)nsplit * 16384 * 64 * 4);
    float* lbuf = mbuf + (size_t)nsplit * 16384;

    hipLaunchKernelGGL(prep_w_kernel, dim3(16, 3), dim3(256), 0, stream, Wq, Wk, Wv, Wt);
    hipLaunchKernelGGL(qkv_kernel, dim3(512), dim3(256), 0, stream, x, Wt, qw, kw, vw);
    if (nsplit == 8)
        hipLaunchKernelGGL(attn_kernel<4>, dim3(16, 8, 8), dim3(256), 0, stream, qw, kw, vw, Op, mbuf, lbuf);
    else if (nsplit == 4)
        hipLaunchKernelGGL(attn_kernel<8>, dim3(16, 8, 4), dim3(256), 0, stream, qw, kw, vw, Op, mbuf, lbuf);
    else if (nsplit == 2)
        hipLaunchKernelGGL(attn_kernel<16>, dim3(16, 8, 2), dim3(256), 0, stream, qw, kw, vw, Op, mbuf, lbuf);
    else
        hipLaunchKernelGGL(attn_kernel<32>, dim3(16, 8, 1), dim3(256), 0, stream, qw, kw, vw, Op, mbuf, lbuf);
    hipLaunchKernelGGL(combine_kernel, dim3(4096), dim3(256), 0, stream, Op, mbuf, lbuf, out, nsplit);
}